// Round 9
// baseline (657.297 us; speedup 1.0000x reference)
//
#include <hip/hip_runtime.h>
#include <hip/hip_bf16.h>

typedef __attribute__((ext_vector_type(8))) __bf16 bf16x8;
typedef __attribute__((ext_vector_type(4))) float f32x4;

__device__ __forceinline__ void gload_lds16(const void* g, void* lds) {
    __builtin_amdgcn_global_load_lds(
        (const __attribute__((address_space(1))) void*)g,
        (__attribute__((address_space(3))) void*)lds, 16, 0, 0);
}

// ---------------------------------------------------------------------------
// int5 block-64 MSE quant-dequant -> bf16 (per-scale reciprocal)
// ---------------------------------------------------------------------------
__global__ __launch_bounds__(256) void quant_bf16_kernel(
    const float* __restrict__ w, __hip_bfloat16* __restrict__ wq, int nblk)
{
#pragma clang fp contract(off)
    int b = blockIdx.x * 256 + threadIdx.x;
    if (b >= nblk) return;
    const float4* src = (const float4*)(w + (size_t)b * 64);
    float v[64];
#pragma unroll
    for (int i = 0; i < 16; ++i) {
        float4 t = src[i];
        v[i*4+0] = t.x; v[i*4+1] = t.y; v[i*4+2] = t.z; v[i*4+3] = t.w;
    }
    float amax = 0.0f;
#pragma unroll
    for (int i = 0; i < 64; ++i) amax = fmaxf(amax, fabsf(v[i]));
    float base = fmaxf(amax, 1e-8f) / 15.0f;

    float best_err = __builtin_inff();
    float best_scale = base, best_rs = 0.0f;
    for (int k = 0; k < 16; ++k) {
        double sd = (k == 15) ? 1.0 : ((double)k * (0.6 / 15.0) + 0.4);
        float scale = base * (float)sd;
        float rs = 1.0f / scale;
        float err = 0.0f;
#pragma unroll
        for (int i = 0; i < 64; ++i) {
            float q = rintf(v[i] * rs);
            q = fminf(fmaxf(q, -15.0f), 15.0f);
            float d = q * scale - v[i];
            err = err + d * d;
        }
        if (err < best_err) { best_err = err; best_scale = scale; best_rs = rs; }
    }
    __hip_bfloat16* dst = wq + (size_t)b * 64;
#pragma unroll
    for (int i = 0; i < 64; ++i) {
        float q = rintf(v[i] * best_rs);
        q = fminf(fmaxf(q, -15.0f), 15.0f);
        dst[i] = __float2bfloat16(q * best_scale);
    }
}

__global__ __launch_bounds__(256) void f32_to_bf16_kernel(
    const float* __restrict__ in, __hip_bfloat16* __restrict__ out, int n8)
{
    int i = blockIdx.x * 256 + threadIdx.x;
    if (i >= n8) return;
    const float4* p = (const float4*)(in + (size_t)i * 8);
    float4 a = p[0], b = p[1];
    alignas(16) __hip_bfloat16 r[8];
    r[0] = __float2bfloat16(a.x); r[1] = __float2bfloat16(a.y);
    r[2] = __float2bfloat16(a.z); r[3] = __float2bfloat16(a.w);
    r[4] = __float2bfloat16(b.x); r[5] = __float2bfloat16(b.y);
    r[6] = __float2bfloat16(b.z); r[7] = __float2bfloat16(b.w);
    *(uint4*)(out + (size_t)i * 8) = *(const uint4*)r;
}

// ---------------------------------------------------------------------------
// 256x128 tile, BK=32, 4 waves (2Mx2N, wave=128x64), 16x16x32 MFMA.
// LDS per buffer 24KB (A 16KB: 256 rows x 64B; B 8KB: 128 rows x 64B),
// double-buffered = 48KB -> 2 blocks/CU (2 independent barrier domains:
// cross-block TLP overlaps one block's LDS drain with the other's MFMAs).
// Swizzle for 64B rows: phys = row*64 + ((k16 ^ ((row>>1)&3))<<4)
//   - frag reads (16 rows x 4 k-slots per 8-lane group): slots all distinct
//     per 8-lane service group -> conflict-free
//   - staging: linear dest (lane*16), inverse-swizzled global source; each
//     4-lane quad covers one full 64B line (permuted granules) -> coalesced
// Schedule per K-tile: stage t+1 (6 gloads) -> read 12 frags -> 32 MFMA ->
// vmcnt(0) -> barrier.  RAW: buf[cur] staged during t-1, drained by every
// wave's vmcnt(0) before the barrier ending t-1. WAR: stagings into
// buf[nxt] overwrite data whose readers finished before that barrier.
// ---------------------------------------------------------------------------
#define SB0() __builtin_amdgcn_sched_barrier(0)
#define BARRIER() { SB0(); __builtin_amdgcn_s_barrier(); SB0(); }
#define STAGE(base, eoff, ldsOff) \
    gload_lds16((base) + (size_t)((eoff) + voff), smem + (ldsOff) + wOff)

template <int EPI>  // 0: C=bf16(relu(acc)^2), 1: C=f32 acc
__global__ __launch_bounds__(256, 2) void gemm256_kernel(
    const __hip_bfloat16* __restrict__ A,   // M x K
    const __hip_bfloat16* __restrict__ B,   // N x K
    void* __restrict__ Cout, int M, int N, int K)
{
    extern __shared__ char smem[];

    const int t    = threadIdx.x;
    const int lane = t & 63;
    const int w    = t >> 6;        // 0..3
    const int wr   = w >> 1;        // 0..1 (128-row half)
    const int wc   = w & 1;         // 0..1 (64-col half)
    const int lo   = lane & 15;
    const int hi   = lane >> 4;
    const uint wOff = (uint)w * 1024u;

    // XCD-aware swizzle (grids are multiples of 8)
    const int cpx = gridDim.x >> 3;
    int bid = blockIdx.x;
    bid = (bid & 7) * cpx + (bid >> 3);
    const int nN = N >> 7;
    const int bm = bid / nN;
    const int bn = bid % nN;
    const int rowBase = bm << 8;    // 256 rows
    const int colBase = bn << 7;    // 128 cols

    const __hip_bfloat16* uA = A + (size_t)rowBase * (size_t)K;
    const __hip_bfloat16* uB = B + (size_t)colBase * (size_t)K;

    // staging source: thread t -> region row t>>2, k16 = (t&3)^((t>>3)&3)
    const uint voff = ((uint)(t >> 2)) * (uint)K
                    + ((((uint)t & 3u) ^ (((uint)t >> 3) & 3u)) * 8u);
    const uint K64 = (uint)K * 64u;     // 64-row stride (elements)

    // fragment read lane offset (swizzled, conflict-free)
    const uint laneOff = (uint)lo * 64u
                       + ((((uint)hi) ^ (((uint)lo >> 1) & 3u)) << 4);
    const uint aFB = (uint)wr * 8192u + laneOff;            // + i*1024
    const uint bFB = 16384u + (uint)wc * 4096u + laneOff;   // + j*1024

    f32x4 acc[8][4] = {};

    // ---- prologue: tile0 -> buf0 ----
    STAGE(uA, 0u,     0u);      STAGE(uA, K64,    4096u);
    STAGE(uA, 2u*K64, 8192u);   STAGE(uA, 3u*K64, 12288u);
    STAGE(uB, 0u,     16384u);  STAGE(uB, K64,    20480u);
    asm volatile("s_waitcnt vmcnt(0)" ::: "memory");
    BARRIER();

    const int NT = K >> 5;
    for (int tt = 0; tt < NT; ++tt) {
        const uint bufOff = (uint)(tt & 1) * 24576u;
        const uint nxtOff = bufOff ^ 24576u;
        const bool pf = (tt + 1 < NT);
        const uint kN = ((uint)(tt + 1)) << 5;

        if (pf) {
            STAGE(uA, kN,          nxtOff + 0u);
            STAGE(uA, kN + K64,    nxtOff + 4096u);
            STAGE(uA, kN + 2u*K64, nxtOff + 8192u);
            STAGE(uA, kN + 3u*K64, nxtOff + 12288u);
            STAGE(uB, kN,          nxtOff + 16384u);
            STAGE(uB, kN + K64,    nxtOff + 20480u);
        }
        SB0();   // pin stagings at tile start

        bf16x8 bfr[4], afr[8];
#pragma unroll
        for (int j = 0; j < 4; ++j)
            bfr[j] = *(const bf16x8*)(smem + bufOff + bFB + (uint)j * 1024u);
#pragma unroll
        for (int i = 0; i < 8; ++i)
            afr[i] = *(const bf16x8*)(smem + bufOff + aFB + (uint)i * 1024u);

        __builtin_amdgcn_s_setprio(1);
#pragma unroll
        for (int i = 0; i < 8; ++i)
#pragma unroll
            for (int j = 0; j < 4; ++j)
                acc[i][j] = __builtin_amdgcn_mfma_f32_16x16x32_bf16(
                    afr[i], bfr[j], acc[i][j], 0, 0, 0);
        __builtin_amdgcn_s_setprio(0);

        if (pf) asm volatile("s_waitcnt vmcnt(0)" ::: "memory");
        BARRIER();
    }

    // ---- epilogue: C/D layout col=lane&15, row=(lane>>4)*4+r ----
    if (EPI == 0) {
        __hip_bfloat16* Cb = (__hip_bfloat16*)Cout;
#pragma unroll
        for (int i = 0; i < 8; ++i)
#pragma unroll
            for (int j = 0; j < 4; ++j)
#pragma unroll
                for (int r = 0; r < 4; ++r) {
                    size_t row = rowBase + wr*128 + i*16 + hi*4 + r;
                    size_t col = colBase + wc*64 + j*16 + lo;
                    float v = fmaxf(acc[i][j][r], 0.0f);
                    Cb[row * N + col] = __float2bfloat16(v * v);
                }
    } else {
        float* Cf = (float*)Cout;
#pragma unroll
        for (int i = 0; i < 8; ++i)
#pragma unroll
            for (int j = 0; j < 4; ++j)
#pragma unroll
                for (int r = 0; r < 4; ++r) {
                    size_t row = rowBase + wr*128 + i*16 + hi*4 + r;
                    size_t col = colBase + wc*64 + j*16 + lo;
                    Cf[row * N + col] = acc[i][j][r];
                }
    }
}

// ---------------------------------------------------------------------------
extern "C" void kernel_launch(void* const* d_in, const int* in_sizes, int n_in,
                              void* d_out, int out_size, void* d_ws, size_t ws_size,
                              hipStream_t stream) {
    const float* x      = (const float*)d_in[0];  // 8192 x 2048
    const float* w_fc   = (const float*)d_in[1];  // 8192 x 2048
    const float* w_proj = (const float*)d_in[2];  // 2048 x 8192
    float* out = (float*)d_out;                   // 8192 x 2048

    const int DIM = 2048, HID = 8192, M = 8192;

    char* ws = (char*)d_ws;
    __hip_bfloat16* Xb  = (__hip_bfloat16*)ws;
    __hip_bfloat16* Wfc = (__hip_bfloat16*)(ws + (size_t)M * DIM * 2);
    __hip_bfloat16* Wpj = (__hip_bfloat16*)(ws + (size_t)(M * DIM + (size_t)HID * DIM) * 2);
    __hip_bfloat16* H2  = (__hip_bfloat16*)(ws + (size_t)(M * DIM + 2 * (size_t)HID * DIM) * 2);

    (void)hipFuncSetAttribute((const void*)gemm256_kernel<0>,
                              hipFuncAttributeMaxDynamicSharedMemorySize, 49152);
    (void)hipFuncSetAttribute((const void*)gemm256_kernel<1>,
                              hipFuncAttributeMaxDynamicSharedMemorySize, 49152);

    int nblk = HID * DIM / 64;
    quant_bf16_kernel<<<nblk / 256, 256, 0, stream>>>(w_fc, Wfc, nblk);
    quant_bf16_kernel<<<nblk / 256, 256, 0, stream>>>(w_proj, Wpj, nblk);

    int n8 = M * DIM / 8;
    f32_to_bf16_kernel<<<n8 / 256, 256, 0, stream>>>(x, Xb, n8);

    // H2 = bf16( relu(X @ Wfc^T)^2 )  [8192 x 8192]
    gemm256_kernel<0><<<(M/256)*(HID/128), 256, 49152, stream>>>(
        Xb, Wfc, (void*)H2, M, HID, DIM);

    // out = H2 @ Wpj^T  [8192 x 2048] f32
    gemm256_kernel<1><<<(M/256)*(DIM/128), 256, 49152, stream>>>(
        H2, Wpj, (void*)out, M, DIM, HID);
}